// Round 1
// baseline (74.345 us; speedup 1.0000x reference)
//
#include <hip/hip_runtime.h>

// TorchSTFT_75419625718337 — STFT -> (mag,phase) -> recombine -> iSTFT.
//
// Algebraic collapse (verified against harness, absmax ~1e-3 << 1.05e-2):
//   recomb == ft exactly (mag*cos(atan2(i,r)) = r, mag*sin(...) = i),
//   fwd_basis^T @ inv_basis = diag(win^2)/scale  (pinv of full-column-rank basis),
//   overlap-add then divides by the same window-sum it multiplied by.
// Net: out[b,0,0,t] = input_data[b,t] — identity.
//
// v2: hipMemcpyAsync in graph capture went through the runtime blit/SDMA
// path at ~0.44 TB/s (73.9 us for 32.8 MB of traffic). Replace with an
// explicit float4 copy kernel: 16 B/lane coalesced, one vector load+store
// per thread. 4,096,000 floats = 1,024,000 float4 = 4000 blocks x 256 thr.
// Roofline: ~5.2 us at 6.3 TB/s + launch overhead.

__global__ __launch_bounds__(256) void copy_identity(
    const float4* __restrict__ in, float4* __restrict__ out, int n4) {
    int i = blockIdx.x * blockDim.x + threadIdx.x;
    if (i < n4) {
        out[i] = in[i];
    }
}

extern "C" void kernel_launch(void* const* d_in, const int* in_sizes, int n_in,
                              void* d_out, int out_size, void* d_ws, size_t ws_size,
                              hipStream_t stream) {
    (void)in_sizes; (void)n_in; (void)d_ws; (void)ws_size;
    const float4* input_data = (const float4*)d_in[0];
    float4* out = (float4*)d_out;

    const int n4 = out_size / 4;              // 1,024,000 (out_size = 4,096,000)
    const int threads = 256;
    const int blocks = (n4 + threads - 1) / threads;  // 4000

    hipLaunchKernelGGL(copy_identity, dim3(blocks), dim3(threads), 0, stream,
                       input_data, out, n4);
}